// Round 5
// baseline (459.137 us; speedup 1.0000x reference)
//
#include <hip/hip_runtime.h>

// residualBlock: two sparse 3x3x3 convs (gather-GEMM over 27 offsets), ReLU
// between, residual add. bf16 MFMA.
//
// R11 = BARRIER-FREE conv: B fragments read DIRECTLY from global (Wta is
// 221KB, L2-resident; 8KB/k-slice), no W LDS staging, no main-loop
// __syncthreads, per-wave epilogue LDS regions (no aliasing -> no epilogue
// barriers either). Gathers UNMASKED (sentinel -> zero row) so every
// outstanding-load count is static and the compiler emits precise vmcnt(N)
// instead of conservative drains. Waves fully decoupled start-to-finish.
//
// Journal:
//  R7  (CHUNK=3, masked, LDS-W): 88.5us/conv BEST. MfmaUtil 25, all pipes idle.
//  R8  (K-split): occupancy 20->30% but 2.6x slower. Occupancy not limiter.
//  R9  (unmasked alone): +9us -- unmasked costs TA work, paid nothing because
//      the 18 barrier-drains still killed the pipeline.
//  R10 (reg-dbuf W): VGPR cap is HARD at 128 arch (+64 acc); wreg spilled
//      (WRITE +40MB). Register-based deepening impossible.
//  R11 tests the remaining fork: barrier-drain co-limit (expect 55-70us/conv)
//      vs MSHR miss-concurrency roofline ~1.11M rows * 2 64B-misses /256CU
//      * ~25cy =~ 91us/conv (expect no change -> declare roofline).
//
// ws layout (~95.9 MB):
//   xb  : bf16 x, (N+1) x 64   (row N = zeros, sentinel)      33,554,560 B
//   yb  : bf16 relu(conv1), (N+1) x 64 (row N = zeros)        33,554,560 B
//   Wta : bf16 Wa^T [k][j][i]                                    221,184 B
//   Wtb : bf16 Wb^T [k][j][i]                                    221,184 B
//   nbrT: int  [27][N]                                        28,311,552 B

#define N_ROWS 262144
#define HCH    64
#define KOFF   27

typedef unsigned short u16;
typedef __attribute__((ext_vector_type(8))) short short8;   // 8 bf16 (4 VGPRs)
typedef __attribute__((ext_vector_type(4))) float f32x4;    // 4 fp32 acc

__device__ __forceinline__ u16 f2bf(float f) {
    unsigned u = __builtin_bit_cast(unsigned, f);
    unsigned r = (u + 0x7FFFu + ((u >> 16) & 1u)) >> 16;   // RNE
    return (u16)r;
}
__device__ __forceinline__ float bf2f(u16 h) {
    return __builtin_bit_cast(float, (unsigned)h << 16);
}
__device__ __forceinline__ unsigned pack2(float a, float b) {
    return (unsigned)f2bf(a) | ((unsigned)f2bf(b) << 16);
}

// ------------------------------------------------------------------ prep ----
// One fused dispatch: [0,8193) prep_x ; [8193,9057) prep_w ; [9057,17249) nbrT
__global__ void prep_all(const float* __restrict__ x, u16* __restrict__ xb,
                         u16* __restrict__ yb,
                         const float* __restrict__ Wa, const float* __restrict__ Wb,
                         u16* __restrict__ Wta, u16* __restrict__ Wtb,
                         const int* __restrict__ nbr, int* __restrict__ nbrT) {
    const int b = blockIdx.x;
    if (b < 8193) {
        long gid = (long)b * 256 + threadIdx.x;             // 8-elem chunks
        const long total = (long)N_ROWS * HCH / 8;          // 2,097,152
        if (gid < total) {
            const float4* s = (const float4*)(x + gid * 8);
            float4 a = s[0], c = s[1];
            uint4 v;
            v.x = pack2(a.x, a.y); v.y = pack2(a.z, a.w);
            v.z = pack2(c.x, c.y); v.w = pack2(c.z, c.w);
            *(uint4*)(xb + gid * 8) = v;
        } else if (gid < total + HCH / 8) {                 // zero row N
            long c = gid - total;
            uint4 z; z.x = 0; z.y = 0; z.z = 0; z.w = 0;
            *(uint4*)(xb + (long)N_ROWS * HCH + c * 8) = z;
            *(uint4*)(yb + (long)N_ROWS * HCH + c * 8) = z;
        }
    } else if (b < 9057) {
        int gid = (b - 8193) * 256 + threadIdx.x;
        const int total = KOFF * HCH * HCH;                 // 110592
        const float* src; u16* dst; int e;
        if (gid < total)          { src = Wa; dst = Wta; e = gid; }
        else if (gid < 2 * total) { src = Wb; dst = Wtb; e = gid - total; }
        else return;
        int k = e >> 12, i = (e >> 6) & 63, j = e & 63;
        dst[(k << 12) + (j << 6) + i] = f2bf(src[e]);
    } else {
        __shared__ int t[32 * 27];
        const int rowbase = (b - 9057) * 32;
        for (int e = threadIdx.x; e < 32 * 27; e += 256)
            t[e] = nbr[(size_t)rowbase * KOFF + e];
        __syncthreads();
        for (int e = threadIdx.x; e < 32 * 27; e += 256) {
            int k = e >> 5, r = e & 31;
            nbrT[(size_t)k * N_ROWS + rowbase + r] = t[r * KOFF + k];
        }
    }
}

// ------------------------------------------------------------------ conv ----
template <bool FIRST>
__global__ __launch_bounds__(256, 2) void conv_kernel(
    const u16* __restrict__ xg,      // gathered-from features, (N+1) x 64 bf16
    const u16* __restrict__ Wt,      // [27][64][64] bf16, [k][j][i]
    const int* __restrict__ nb,      // nbrT[27][N]
    u16* __restrict__ ybf,           // FIRST: relu output bf16
    float* __restrict__ outf,        // !FIRST: final fp32 output
    const u16* __restrict__ residb)  // !FIRST: residual x (bf16)
{
    __shared__ float Fsh[4 * 16 * 68];                      // 17,408 B epilogue

    const int tid  = threadIdx.x;
    const int wave = tid >> 6;
    const int lane = tid & 63;
    const int m    = lane & 15;      // A row / B col / C col
    const int q    = lane >> 4;      // K-subgroup
    const int base = blockIdx.x * 256 + wave * 64;

    int row[4];
#pragma unroll
    for (int t = 0; t < 4; t++) row[t] = base + t * 16 + m;

    auto ld_idx = [&](int k, int t) -> int {
        return nb[(size_t)k * N_ROWS + row[t]];
    };

    // UNCONDITIONAL gather: sentinel idx = N_ROWS hits the zero row. Keeps
    // the outstanding-vmem count static -> precise compiler vmcnt(N).
    auto ldA = [&](int idx, short8& a0, short8& a1) {
        const u16* ar = xg + (size_t)idx * HCH + q * 8;
        a0 = *(const short8*)ar;
        a1 = *(const short8*)(ar + 32);
    };

    // per-lane constant part of the B address (B read straight from global)
    const u16* bbase = Wt + m * 64 + q * 8;

    f32x4 acc[4][4];
#pragma unroll
    for (int t = 0; t < 4; t++)
#pragma unroll
        for (int jt = 0; jt < 4; jt++)
            acc[t][jt] = (f32x4){0.f, 0.f, 0.f, 0.f};

    // ---- pipeline prologue: idx(0..3), A(0), A(1) in flight ----
    int i0[4], i1[4], idxRing[2][4];
#pragma unroll
    for (int t = 0; t < 4; t++) i0[t] = ld_idx(0, t);
#pragma unroll
    for (int t = 0; t < 4; t++) i1[t] = ld_idx(1, t);
#pragma unroll
    for (int t = 0; t < 4; t++) idxRing[0][t] = ld_idx(2, t);
#pragma unroll
    for (int t = 0; t < 4; t++) idxRing[1][t] = ld_idx(3, t);

    short8 Aring[3][4][2];
#pragma unroll
    for (int t = 0; t < 4; t++) ldA(i0[t], Aring[0][t][0], Aring[0][t][1]);
#pragma unroll
    for (int t = 0; t < 4; t++) ldA(i1[t], Aring[1][t][0], Aring[1][t][1]);

    // ---- main loop: NO barriers, NO LDS. Per step (all counts static):
    //  [B0 issue][A(kk+2) issue][idx(kk+4) issue][B1 issue]
    //  [16 MFMA h0 (covers B1 latency)][16 MFMA h1]
#pragma unroll 3
    for (int kk = 0; kk < KOFF; kk++) {
        const int par = kk & 1;
        const int cur = kk % 3;
        const int nxt = (kk + 2) % 3;
        const u16* bs = bbase + kk * 4096;

        short8 B0[4], B1[4];
#pragma unroll
        for (int jt = 0; jt < 4; jt++)
            B0[jt] = *(const short8*)(bs + jt * 1024);

        // issue A(kk+2) (indices arrived 2 iters ago), unconditional
#pragma unroll
        for (int t = 0; t < 4; t++)
            ldA(idxRing[par][t], Aring[nxt][t][0], Aring[nxt][t][1]);
        // issue idx(kk+4)
        const int k4 = (kk + 4 < KOFF) ? kk + 4 : KOFF - 1;
#pragma unroll
        for (int t = 0; t < 4; t++) idxRing[par][t] = ld_idx(k4, t);

#pragma unroll
        for (int jt = 0; jt < 4; jt++)
            B1[jt] = *(const short8*)(bs + jt * 1024 + 32);

        // 32 MFMAs: all h0 (independent), then all h1
#pragma unroll
        for (int t = 0; t < 4; t++)
#pragma unroll
            for (int jt = 0; jt < 4; jt++)
                acc[t][jt] = __builtin_amdgcn_mfma_f32_16x16x32_bf16(
                    Aring[cur][t][0], B0[jt], acc[t][jt], 0, 0, 0);
#pragma unroll
        for (int t = 0; t < 4; t++)
#pragma unroll
            for (int jt = 0; jt < 4; jt++)
                acc[t][jt] = __builtin_amdgcn_mfma_f32_16x16x32_bf16(
                    Aring[cur][t][1], B1[jt], acc[t][jt], 0, 0, 0);
    }

    // ---- epilogue: transpose through per-wave LDS region (disjoint ->
    // wave-local lgkmcnt ordering suffices; NO barriers) ----
    float* sl = Fsh + wave * (16 * 68);                     // 4,352 B/wave
    const int r = lane & 15;                                // local row
    const int h = lane >> 4;                                // 16-col segment
#pragma unroll
    for (int t = 0; t < 4; t++) {
#pragma unroll
        for (int jt = 0; jt < 4; jt++)
#pragma unroll
            for (int rr = 0; rr < 4; rr++)
                sl[(q * 4 + rr) * 68 + jt * 16 + m] = acc[t][jt][rr];

        float4 v0 = *(const float4*)&sl[r * 68 + h * 16 + 0];
        float4 v1 = *(const float4*)&sl[r * 68 + h * 16 + 4];
        float4 v2 = *(const float4*)&sl[r * 68 + h * 16 + 8];
        float4 v3 = *(const float4*)&sl[r * 68 + h * 16 + 12];
        const size_t grow = (size_t)(base + t * 16 + r);
        if (FIRST) {
            uint4 o0, o1;
            o0.x = pack2(fmaxf(v0.x, 0.f), fmaxf(v0.y, 0.f));
            o0.y = pack2(fmaxf(v0.z, 0.f), fmaxf(v0.w, 0.f));
            o0.z = pack2(fmaxf(v1.x, 0.f), fmaxf(v1.y, 0.f));
            o0.w = pack2(fmaxf(v1.z, 0.f), fmaxf(v1.w, 0.f));
            o1.x = pack2(fmaxf(v2.x, 0.f), fmaxf(v2.y, 0.f));
            o1.y = pack2(fmaxf(v2.z, 0.f), fmaxf(v2.w, 0.f));
            o1.z = pack2(fmaxf(v3.x, 0.f), fmaxf(v3.y, 0.f));
            o1.w = pack2(fmaxf(v3.z, 0.f), fmaxf(v3.w, 0.f));
            uint4* dst = (uint4*)(ybf + grow * HCH + h * 16);
            dst[0] = o0; dst[1] = o1;
        } else {
            const uint4* rb = (const uint4*)(residb + grow * HCH + h * 16);
            uint4 r0 = rb[0], r1 = rb[1];
            float4 o;
            float* op = outf + grow * HCH + h * 16;
            o.x = v0.x + bf2f((u16)(r0.x & 0xFFFF));
            o.y = v0.y + bf2f((u16)(r0.x >> 16));
            o.z = v0.z + bf2f((u16)(r0.y & 0xFFFF));
            o.w = v0.w + bf2f((u16)(r0.y >> 16));
            *(float4*)(op + 0) = o;
            o.x = v1.x + bf2f((u16)(r0.z & 0xFFFF));
            o.y = v1.y + bf2f((u16)(r0.z >> 16));
            o.z = v1.z + bf2f((u16)(r0.w & 0xFFFF));
            o.w = v1.w + bf2f((u16)(r0.w >> 16));
            *(float4*)(op + 4) = o;
            o.x = v2.x + bf2f((u16)(r1.x & 0xFFFF));
            o.y = v2.y + bf2f((u16)(r1.x >> 16));
            o.z = v2.z + bf2f((u16)(r1.y & 0xFFFF));
            o.w = v2.w + bf2f((u16)(r1.y >> 16));
            *(float4*)(op + 8) = o;
            o.x = v3.x + bf2f((u16)(r1.z & 0xFFFF));
            o.y = v3.y + bf2f((u16)(r1.z >> 16));
            o.z = v3.z + bf2f((u16)(r1.w & 0xFFFF));
            o.w = v3.w + bf2f((u16)(r1.w >> 16));
            *(float4*)(op + 12) = o;
        }
        // WAR between t-iterations is wave-local; compiler inserts lgkmcnt.
    }
}

// ---------------------------------------------------------------- launch ----
extern "C" void kernel_launch(void* const* d_in, const int* in_sizes, int n_in,
                              void* d_out, int out_size, void* d_ws, size_t ws_size,
                              hipStream_t stream) {
    const float* x   = (const float*)d_in[0];
    const float* Wa  = (const float*)d_in[1];
    const float* Wb  = (const float*)d_in[2];
    const int*   nbr = (const int*)d_in[3];
    float* out = (float*)d_out;

    char* ws = (char*)d_ws;
    const size_t xb_bytes = (size_t)(N_ROWS + 1) * HCH * sizeof(u16); // 33,554,560
    const size_t w_bytes  = (size_t)KOFF * HCH * HCH * sizeof(u16);   //    221,184
    u16* xb  = (u16*)ws;
    u16* yb  = (u16*)(ws + xb_bytes);
    u16* Wta = (u16*)(ws + 2 * xb_bytes);
    u16* Wtb = (u16*)(ws + 2 * xb_bytes + w_bytes);
    int* nbrT = (int*)(ws + 2 * xb_bytes + 2 * w_bytes);

    prep_all<<<17249, 256, 0, stream>>>(x, xb, yb, Wa, Wb, Wta, Wtb, nbr, nbrT);
    conv_kernel<true ><<<N_ROWS / 256, 256, 0, stream>>>(xb, Wta, nbrT, yb, nullptr, nullptr);
    conv_kernel<false><<<N_ROWS / 256, 256, 0, stream>>>(yb, Wtb, nbrT, nullptr, out, xb);
}

// Round 6
// 274.681 us; speedup vs baseline: 1.6715x; 1.6715x over previous
//
#include <hip/hip_runtime.h>

// residualBlock: two sparse 3x3x3 convs (gather-GEMM over 27 offsets), ReLU
// between, residual add. bf16 MFMA.
//
// R12 = R7 + W double-buffer via global_load_lds (VGPR-free staging).
// Per chunk: issue 6 glds (chunk c+1 -> idle 24KB buf, pre-swizzled GLOBAL
// source so the linear lane*16 LDS write lands swizzled) at chunk top; W
// latency hides under the 3 MFMA steps; ONE __syncthreads per chunk (its
// vmcnt drain doubles as glds completion). Barriers 18->9/block, W latency
// off the critical path, no staging registers (R10's spill trap avoided).
//
// Journal:
//  R7  (CHUNK=3, masked, LDS-W, 2 barriers/chunk): 88.5us/conv BEST.
//  R8  (K-split): occ 20->30% but 2.6x slower. Occupancy not the limiter.
//  R9  (unmasked): +9us. TA lane-request rate is a real resource; masks stay.
//  R10 (reg-dbuf W): VGPR cap HARD at 128 arch + 64 acc; wreg spilled.
//  R11 (B-from-global, no barriers): 173us. B must come from LDS; vmem
//      dependency in front of MFMA + 56M extra TA requests = disaster.
// Spill tripwire: FETCH/WRITE balloon -> revert.
//
// ws layout (~95.9 MB):
//   xb  : bf16 x, (N+1) x 64   (row N = zeros, sentinel)      33,554,560 B
//   yb  : bf16 relu(conv1), (N+1) x 64 (row N = zeros)        33,554,560 B
//   Wta : bf16 Wa^T [k][j][i]                                    221,184 B
//   Wtb : bf16 Wb^T [k][j][i]                                    221,184 B
//   nbrT: int  [27][N]                                        28,311,552 B

#define N_ROWS 262144
#define HCH    64
#define KOFF   27
#define CHUNK  3

typedef unsigned short u16;
typedef __attribute__((ext_vector_type(8))) short short8;   // 8 bf16 (4 VGPRs)
typedef __attribute__((ext_vector_type(4))) float f32x4;    // 4 fp32 acc

__device__ __forceinline__ u16 f2bf(float f) {
    unsigned u = __builtin_bit_cast(unsigned, f);
    unsigned r = (u + 0x7FFFu + ((u >> 16) & 1u)) >> 16;   // RNE
    return (u16)r;
}
__device__ __forceinline__ float bf2f(u16 h) {
    return __builtin_bit_cast(float, (unsigned)h << 16);
}
__device__ __forceinline__ unsigned pack2(float a, float b) {
    return (unsigned)f2bf(a) | ((unsigned)f2bf(b) << 16);
}

// ------------------------------------------------------------------ prep ----
// One fused dispatch: [0,8193) prep_x ; [8193,9057) prep_w ; [9057,17249) nbrT
__global__ void prep_all(const float* __restrict__ x, u16* __restrict__ xb,
                         u16* __restrict__ yb,
                         const float* __restrict__ Wa, const float* __restrict__ Wb,
                         u16* __restrict__ Wta, u16* __restrict__ Wtb,
                         const int* __restrict__ nbr, int* __restrict__ nbrT) {
    const int b = blockIdx.x;
    if (b < 8193) {
        long gid = (long)b * 256 + threadIdx.x;             // 8-elem chunks
        const long total = (long)N_ROWS * HCH / 8;          // 2,097,152
        if (gid < total) {
            const float4* s = (const float4*)(x + gid * 8);
            float4 a = s[0], c = s[1];
            uint4 v;
            v.x = pack2(a.x, a.y); v.y = pack2(a.z, a.w);
            v.z = pack2(c.x, c.y); v.w = pack2(c.z, c.w);
            *(uint4*)(xb + gid * 8) = v;
        } else if (gid < total + HCH / 8) {                 // zero row N
            long c = gid - total;
            uint4 z; z.x = 0; z.y = 0; z.z = 0; z.w = 0;
            *(uint4*)(xb + (long)N_ROWS * HCH + c * 8) = z;
            *(uint4*)(yb + (long)N_ROWS * HCH + c * 8) = z;
        }
    } else if (b < 9057) {
        int gid = (b - 8193) * 256 + threadIdx.x;
        const int total = KOFF * HCH * HCH;                 // 110592
        const float* src; u16* dst; int e;
        if (gid < total)          { src = Wa; dst = Wta; e = gid; }
        else if (gid < 2 * total) { src = Wb; dst = Wtb; e = gid - total; }
        else return;
        int k = e >> 12, i = (e >> 6) & 63, j = e & 63;
        dst[(k << 12) + (j << 6) + i] = f2bf(src[e]);
    } else {
        __shared__ int t[32 * 27];
        const int rowbase = (b - 9057) * 32;
        for (int e = threadIdx.x; e < 32 * 27; e += 256)
            t[e] = nbr[(size_t)rowbase * KOFF + e];
        __syncthreads();
        for (int e = threadIdx.x; e < 32 * 27; e += 256) {
            int k = e >> 5, r = e & 31;
            nbrT[(size_t)k * N_ROWS + rowbase + r] = t[r * KOFF + k];
        }
    }
}

// ------------------------------------------------------------------ conv ----
template <bool FIRST>
__global__ __launch_bounds__(256, 2) void conv_kernel(
    const u16* __restrict__ xg,      // gathered-from features, (N+1) x 64 bf16
    const u16* __restrict__ Wt,      // [27][64][64] bf16, [k][j][i]
    const int* __restrict__ nb,      // nbrT[27][N]
    u16* __restrict__ ybf,           // FIRST: relu output bf16
    float* __restrict__ outf,        // !FIRST: final fp32 output
    const u16* __restrict__ residb)  // !FIRST: residual x (bf16)
{
    __shared__ uint4 Wlds4[2 * CHUNK * 512];                // 49,152 B (dbuf)
    float* Fsh = (float*)Wlds4;                             // epilogue alias

    const int tid  = threadIdx.x;
    const int wave = tid >> 6;
    const int lane = tid & 63;
    const int m    = lane & 15;      // A row / B col / C col
    const int q    = lane >> 4;      // K-subgroup
    const int base = blockIdx.x * 256 + wave * 64;

    int row[4];
#pragma unroll
    for (int t = 0; t < 4; t++) row[t] = base + t * 16 + m;

    auto ld_idx = [&](int k, int t) -> int {
        return nb[(size_t)k * N_ROWS + row[t]];
    };

    // masked gather: sentinel lanes are exec-masked off -> no addresses issued
    auto ldA = [&](int idx, short8& a0, short8& a1) {
        short8 z = {0, 0, 0, 0, 0, 0, 0, 0};
        a0 = z; a1 = z;
        if (idx != N_ROWS) {
            const u16* ar = xg + (size_t)idx * HCH + q * 8;
            a0 = *(const short8*)ar;
            a1 = *(const short8*)(ar + 32);
        }
    };

    // VGPR-free W staging: global_load_lds writes LDS linearly (uniform base
    // + lane*16), so the swizzle is applied to the GLOBAL source address.
    // Slot p (uint4) holds W element e = (p&~7)|((p&7)^((p>>3)&7)) -- the
    // XOR is self-inverse, matching the ds_read side's (cc ^ (j&7)).
    auto stageW = [&](int c, int bufSel) {
        const char* gbase = (const char*)(Wt + (size_t)c * CHUNK * 4096);
        uint4* bufBase = Wlds4 + bufSel * (CHUNK * 512);
#pragma unroll
        for (int i = 0; i < 6; i++) {
            int p = i * 256 + wave * 64 + lane;
            int e = (p & ~7) | ((p & 7) ^ ((p >> 3) & 7));
            const unsigned* src = (const unsigned*)(gbase + (size_t)e * 16);
            unsigned* dst = (unsigned*)(bufBase + i * 256 + wave * 64);
            __builtin_amdgcn_global_load_lds(
                (const __attribute__((address_space(1))) unsigned*)src,
                (__attribute__((address_space(3))) unsigned*)dst,
                16, 0, 0);
        }
    };

    f32x4 acc[4][4];
#pragma unroll
    for (int t = 0; t < 4; t++)
#pragma unroll
        for (int jt = 0; jt < 4; jt++)
            acc[t][jt] = (f32x4){0.f, 0.f, 0.f, 0.f};

    // ---- prologue: W(0) glds first (oldest), then idx(0..3), A(0), A(1) ----
    stageW(0, 0);

    int i0[4], i1[4], idxRing[2][4];
#pragma unroll
    for (int t = 0; t < 4; t++) i0[t] = ld_idx(0, t);
#pragma unroll
    for (int t = 0; t < 4; t++) i1[t] = ld_idx(1, t);
#pragma unroll
    for (int t = 0; t < 4; t++) idxRing[0][t] = ld_idx(2, t);
#pragma unroll
    for (int t = 0; t < 4; t++) idxRing[1][t] = ld_idx(3, t);

    short8 Aring[3][4][2];
#pragma unroll
    for (int t = 0; t < 4; t++) ldA(i0[t], Aring[0][t][0], Aring[0][t][1]);
#pragma unroll
    for (int t = 0; t < 4; t++) ldA(i1[t], Aring[1][t][0], Aring[1][t][1]);

    __syncthreads();                                        // W(0) landed

#pragma unroll
    for (int c = 0; c < KOFF / CHUNK; c++) {
        const int buf = c & 1;
        // issue W(c+1) -> idle buffer; latency hides under 3 MFMA steps
        if (c + 1 < KOFF / CHUNK) stageW(c + 1, buf ^ 1);

        const u16* WshC = (const u16*)(Wlds4 + buf * (CHUNK * 512));
#pragma unroll
        for (int s = 0; s < CHUNK; s++) {
            const int kk  = c * CHUNK + s;
            const int par = kk & 1;
            const int cur = kk % 3;
            const int nxt = (kk + 2) % 3;

            // issue A(kk+2) (indices arrived 2 iters ago), exec-masked
#pragma unroll
            for (int t = 0; t < 4; t++)
                ldA(idxRing[par][t], Aring[nxt][t][0], Aring[nxt][t][1]);
            // issue idx(kk+4)
            const int k4 = (kk + 4 < KOFF) ? kk + 4 : KOFF - 1;
#pragma unroll
            for (int t = 0; t < 4; t++) idxRing[par][t] = ld_idx(k4, t);

            // B frags from swizzled LDS (conflict-free b128)
            const u16* bs = WshC + s * 4096;
            short8 B0[4], B1[4];
#pragma unroll
            for (int jt = 0; jt < 4; jt++) {
                int j = jt * 16 + m;
                B0[jt] = *(const short8*)(bs + j * 64 + ((q    ) ^ (m & 7)) * 8);
                B1[jt] = *(const short8*)(bs + j * 64 + ((q + 4) ^ (m & 7)) * 8);
            }

            // 32 MFMAs: all h0 (independent), then all h1
#pragma unroll
            for (int t = 0; t < 4; t++)
#pragma unroll
                for (int jt = 0; jt < 4; jt++)
                    acc[t][jt] = __builtin_amdgcn_mfma_f32_16x16x32_bf16(
                        Aring[cur][t][0], B0[jt], acc[t][jt], 0, 0, 0);
#pragma unroll
            for (int t = 0; t < 4; t++)
#pragma unroll
                for (int jt = 0; jt < 4; jt++)
                    acc[t][jt] = __builtin_amdgcn_mfma_f32_16x16x32_bf16(
                        Aring[cur][t][1], B1[jt], acc[t][jt], 0, 0, 0);
        }

        // single barrier per chunk: swaps buffers; its vmcnt drain also
        // guarantees the glds for chunk c+1 have landed in LDS.
        __syncthreads();
    }

    // ---- epilogue: transpose through LDS, store full 128B lines ----
    float* sl = Fsh + wave * (16 * 68);                     // 4,352 B/wave
    const int r = lane & 15;                                // local row
    const int h = lane >> 4;                                // 16-col segment
#pragma unroll
    for (int t = 0; t < 4; t++) {
        __syncthreads();
#pragma unroll
        for (int jt = 0; jt < 4; jt++)
#pragma unroll
            for (int rr = 0; rr < 4; rr++)
                sl[(q * 4 + rr) * 68 + jt * 16 + m] = acc[t][jt][rr];
        __syncthreads();

        float4 v0 = *(const float4*)&sl[r * 68 + h * 16 + 0];
        float4 v1 = *(const float4*)&sl[r * 68 + h * 16 + 4];
        float4 v2 = *(const float4*)&sl[r * 68 + h * 16 + 8];
        float4 v3 = *(const float4*)&sl[r * 68 + h * 16 + 12];
        const size_t grow = (size_t)(base + t * 16 + r);
        if (FIRST) {
            uint4 o0, o1;
            o0.x = pack2(fmaxf(v0.x, 0.f), fmaxf(v0.y, 0.f));
            o0.y = pack2(fmaxf(v0.z, 0.f), fmaxf(v0.w, 0.f));
            o0.z = pack2(fmaxf(v1.x, 0.f), fmaxf(v1.y, 0.f));
            o0.w = pack2(fmaxf(v1.z, 0.f), fmaxf(v1.w, 0.f));
            o1.x = pack2(fmaxf(v2.x, 0.f), fmaxf(v2.y, 0.f));
            o1.y = pack2(fmaxf(v2.z, 0.f), fmaxf(v2.w, 0.f));
            o1.z = pack2(fmaxf(v3.x, 0.f), fmaxf(v3.y, 0.f));
            o1.w = pack2(fmaxf(v3.z, 0.f), fmaxf(v3.w, 0.f));
            uint4* dst = (uint4*)(ybf + grow * HCH + h * 16);
            dst[0] = o0; dst[1] = o1;
        } else {
            const uint4* rb = (const uint4*)(residb + grow * HCH + h * 16);
            uint4 r0 = rb[0], r1 = rb[1];
            float4 o;
            float* op = outf + grow * HCH + h * 16;
            o.x = v0.x + bf2f((u16)(r0.x & 0xFFFF));
            o.y = v0.y + bf2f((u16)(r0.x >> 16));
            o.z = v0.z + bf2f((u16)(r0.y & 0xFFFF));
            o.w = v0.w + bf2f((u16)(r0.y >> 16));
            *(float4*)(op + 0) = o;
            o.x = v1.x + bf2f((u16)(r0.z & 0xFFFF));
            o.y = v1.y + bf2f((u16)(r0.z >> 16));
            o.z = v1.z + bf2f((u16)(r0.w & 0xFFFF));
            o.w = v1.w + bf2f((u16)(r0.w >> 16));
            *(float4*)(op + 4) = o;
            o.x = v2.x + bf2f((u16)(r1.x & 0xFFFF));
            o.y = v2.y + bf2f((u16)(r1.x >> 16));
            o.z = v2.z + bf2f((u16)(r1.y & 0xFFFF));
            o.w = v2.w + bf2f((u16)(r1.y >> 16));
            *(float4*)(op + 8) = o;
            o.x = v3.x + bf2f((u16)(r1.z & 0xFFFF));
            o.y = v3.y + bf2f((u16)(r1.z >> 16));
            o.z = v3.z + bf2f((u16)(r1.w & 0xFFFF));
            o.w = v3.w + bf2f((u16)(r1.w >> 16));
            *(float4*)(op + 12) = o;
        }
    }
}

// ---------------------------------------------------------------- launch ----
extern "C" void kernel_launch(void* const* d_in, const int* in_sizes, int n_in,
                              void* d_out, int out_size, void* d_ws, size_t ws_size,
                              hipStream_t stream) {
    const float* x   = (const float*)d_in[0];
    const float* Wa  = (const float*)d_in[1];
    const float* Wb  = (const float*)d_in[2];
    const int*   nbr = (const int*)d_in[3];
    float* out = (float*)d_out;

    char* ws = (char*)d_ws;
    const size_t xb_bytes = (size_t)(N_ROWS + 1) * HCH * sizeof(u16); // 33,554,560
    const size_t w_bytes  = (size_t)KOFF * HCH * HCH * sizeof(u16);   //    221,184
    u16* xb  = (u16*)ws;
    u16* yb  = (u16*)(ws + xb_bytes);
    u16* Wta = (u16*)(ws + 2 * xb_bytes);
    u16* Wtb = (u16*)(ws + 2 * xb_bytes + w_bytes);
    int* nbrT = (int*)(ws + 2 * xb_bytes + 2 * w_bytes);

    prep_all<<<17249, 256, 0, stream>>>(x, xb, yb, Wa, Wb, Wta, Wtb, nbr, nbrT);
    conv_kernel<true ><<<N_ROWS / 256, 256, 0, stream>>>(xb, Wta, nbrT, yb, nullptr, nullptr);
    conv_kernel<false><<<N_ROWS / 256, 256, 0, stream>>>(yb, Wtb, nbrT, nullptr, out, xb);
}